// Round 1
// baseline (164.670 us; speedup 1.0000x reference)
//
#include <hip/hip_runtime.h>

#define B_  8
#define TE_ 256
#define TD_ 128
#define HE_ 512

// tanh(x) = 1 - 2/(exp(2x)+1); safe at +/-inf, err ~1e-6 (v_exp + v_rcp)
__device__ __forceinline__ float fast_tanh(float x) {
  float e = __expf(2.0f * x);
  return 1.0f - 2.0f * __builtin_amdgcn_rcpf(e + 1.0f);
}

// C[M,512] = A[M,512] @ B[512,512], fp32 tiled: BM=BN=64, BK=16, 256 thr, 4x4/thread.
// One launch does both GEMMs: blockIdx.y < 32 -> Ws = enc@Wa (M=2048), else Uh = dec@Ua (M=1024).
__global__ __launch_bounds__(256) void gemm_pair(
    const float* __restrict__ enc, const float* __restrict__ dec,
    const float* __restrict__ Wa, const float* __restrict__ Ua,
    float* __restrict__ Ws, float* __restrict__ Uh) {
  __shared__ float sA[16][64];   // sA[k][m]
  __shared__ float sB[16][64];   // sB[k][n]
  const int tid = threadIdx.x;
  const float* A; const float* Bw; float* C;
  int rb = blockIdx.y;
  if (rb < 32) { A = enc; Bw = Wa; C = Ws; }
  else         { A = dec; Bw = Ua; C = Uh; rb -= 32; }
  const int bm = rb * 64;
  const int bn = blockIdx.x * 64;
  const int r4   = (tid >> 4) << 2;   // output row group
  const int c4   = (tid & 15) << 2;   // output col group
  const int arow = tid >> 2;          // A-tile row to load
  const int acol = (tid & 3) << 2;    // A-tile k-offset (float4)
  const int bkr  = tid >> 4;          // B-tile k row
  const int bcol = (tid & 15) << 2;   // B-tile n-offset (float4)
  float acc[4][4] = {};
  const float* Ap = A + (size_t)(bm + arow) * 512 + acol;
  const float* Bp = Bw + (size_t)bkr * 512 + bn + bcol;
  for (int k0 = 0; k0 < 512; k0 += 16) {
    const float4 av = *(const float4*)(Ap + k0);
    const float4 bv = *(const float4*)(Bp + (size_t)k0 * 512);
    __syncthreads();
    sA[acol + 0][arow] = av.x;
    sA[acol + 1][arow] = av.y;
    sA[acol + 2][arow] = av.z;
    sA[acol + 3][arow] = av.w;
    *(float4*)&sB[bkr][bcol] = bv;
    __syncthreads();
#pragma unroll
    for (int k = 0; k < 16; ++k) {
      const float4 a = *(const float4*)&sA[k][r4];
      const float4 b = *(const float4*)&sB[k][c4];
      const float ar[4] = {a.x, a.y, a.z, a.w};
      const float br[4] = {b.x, b.y, b.z, b.w};
#pragma unroll
      for (int i = 0; i < 4; ++i)
#pragma unroll
        for (int j = 0; j < 4; ++j)
          acc[i][j] = fmaf(ar[i], br[j], acc[i][j]);
    }
  }
#pragma unroll
  for (int i = 0; i < 4; ++i) {
    const float4 o = {acc[i][0], acc[i][1], acc[i][2], acc[i][3]};
    *(float4*)&C[(size_t)(bm + r4 + i) * 512 + bn + c4] = o;
  }
}

// One block per (b,d). Phase 1: e[t] = sum_h tanh(Ws[b,t,h]+Uh[b,d,h])*V[h]
// (wave handles 64 t's, lanes split h 8-way, shuffle reduce). Phase 2: softmax
// over TE. Phase 3: c[h] = sum_t e[t]*enc[b,t,h].
__global__ __launch_bounds__(256) void attn_fused(
    const float* __restrict__ Ws, const float* __restrict__ Uh,
    const float* __restrict__ Va, const float* __restrict__ enc,
    float* __restrict__ c_out, float* __restrict__ e_out) {
  __shared__ float sUh[HE_];
  __shared__ float sV[HE_];
  __shared__ float sE[TE_];
  __shared__ float red[8];
  const int tid = threadIdx.x;
  const int b = blockIdx.x >> 7;     // / TD_
  const int d = blockIdx.x & 127;    // % TD_
  ((float2*)sUh)[tid] = ((const float2*)(Uh + (size_t)(b * TD_ + d) * HE_))[tid];
  ((float2*)sV)[tid]  = ((const float2*)Va)[tid];
  __syncthreads();
  const int lane = tid & 63;
  const int wv   = tid >> 6;         // wave id 0..3
  const int h0   = lane << 3;        // 8 h per lane
  float uh[8], vv[8];
#pragma unroll
  for (int j = 0; j < 8; ++j) { uh[j] = sUh[h0 + j]; vv[j] = sV[h0 + j]; }
  const float* wsbase = Ws + (size_t)b * TE_ * HE_ + h0;
  for (int ti = 0; ti < 64; ++ti) {
    const int t = (wv << 6) + ti;
    const float4 w0 = *(const float4*)(wsbase + (size_t)t * HE_);
    const float4 w1 = *(const float4*)(wsbase + (size_t)t * HE_ + 4);
    float s;
    s  = fast_tanh(w0.x + uh[0]) * vv[0];
    s += fast_tanh(w0.y + uh[1]) * vv[1];
    s += fast_tanh(w0.z + uh[2]) * vv[2];
    s += fast_tanh(w0.w + uh[3]) * vv[3];
    s += fast_tanh(w1.x + uh[4]) * vv[4];
    s += fast_tanh(w1.y + uh[5]) * vv[5];
    s += fast_tanh(w1.z + uh[6]) * vv[6];
    s += fast_tanh(w1.w + uh[7]) * vv[7];
#pragma unroll
    for (int off = 32; off; off >>= 1) s += __shfl_down(s, off, 64);
    if (lane == 0) sE[t] = s;
  }
  __syncthreads();
  // softmax over sE[0..255]; thread tid owns t=tid
  const float logit = sE[tid];
  float m = logit;
#pragma unroll
  for (int off = 32; off; off >>= 1) m = fmaxf(m, __shfl_down(m, off, 64));
  if (lane == 0) red[wv] = m;
  __syncthreads();
  m = fmaxf(fmaxf(red[0], red[1]), fmaxf(red[2], red[3]));
  const float ex = __expf(logit - m);
  float ssum = ex;
#pragma unroll
  for (int off = 32; off; off >>= 1) ssum += __shfl_down(ssum, off, 64);
  if (lane == 0) red[4 + wv] = ssum;
  __syncthreads();
  ssum = red[4] + red[5] + red[6] + red[7];
  const float wgt = ex / ssum;
  sE[tid] = wgt;
  e_out[(size_t)(b * TD_ + d) * TE_ + tid] = wgt;
  __syncthreads();
  // c[b,d,h] = sum_t e[t] * enc[b,t,h]; thread owns h=tid and h=tid+256
  float a0 = 0.f, a1 = 0.f;
  const float* ep = enc + (size_t)b * TE_ * HE_;
#pragma unroll 4
  for (int t = 0; t < TE_; ++t) {
    const float wt = sE[t];
    a0 = fmaf(wt, ep[(size_t)t * HE_ + tid], a0);
    a1 = fmaf(wt, ep[(size_t)t * HE_ + 256 + tid], a1);
  }
  float* cp = c_out + (size_t)(b * TD_ + d) * HE_;
  cp[tid]       = a0;
  cp[tid + 256] = a1;
}

extern "C" void kernel_launch(void* const* d_in, const int* in_sizes, int n_in,
                              void* d_out, int out_size, void* d_ws, size_t ws_size,
                              hipStream_t stream) {
  const float* enc = (const float*)d_in[0];   // [8,256,512]
  const float* dec = (const float*)d_in[1];   // [8,128,512]
  const float* Wa  = (const float*)d_in[2];   // [512,512]
  const float* Ua  = (const float*)d_in[3];   // [512,512]
  const float* Va  = (const float*)d_in[4];   // [512,1]
  float* c_out = (float*)d_out;                         // 8*128*512
  float* e_out = c_out + (size_t)B_ * TD_ * HE_;        // 8*128*256
  float* Ws = (float*)d_ws;                             // 2048*512 fp32 (4 MB)
  float* Uh = Ws + (size_t)B_ * TE_ * HE_;              // 1024*512 fp32 (2 MB)
  gemm_pair<<<dim3(8, 48), 256, 0, stream>>>(enc, dec, Wa, Ua, Ws, Uh);
  attn_fused<<<B_ * TD_, 256, 0, stream>>>(Ws, Uh, Va, enc, c_out, e_out);
}